// Round 21
// baseline (168.111 us; speedup 1.0000x reference)
//
#include <hip/hip_runtime.h>
#include <hip/hip_fp16.h>
#include <cstdint>
#include <cstddef>

#define DIM_IN 128
#define DIM_HID 64
#define MS_TILE 16384     // edges per multisplit tile; runs = MS_TILE/NB ~ 84 edges
#define OVF_CAP 32768     // overflow valve capacity (edges)
#define BSH 9             // bin shift: 512-node bins
#define BINSZ 512
#define MAXNB 512
#define CAPL 20480        // LDS stage (80KB); bin mean 16327, ~32 sigma headroom

// native clang vectors (nontemporal builtins reject HIP_vector_type classes)
typedef int v2i __attribute__((ext_vector_type(2)));

__device__ inline __half2 h2_shfl_xor(__half2 v, int m) {
    int i = __shfl_xor(*reinterpret_cast<int*>(&v), m, 32);
    return *reinterpret_cast<__half2*>(&i);
}
__device__ inline __half2 u2h(unsigned int u) {
    return *reinterpret_cast<__half2*>(&u);
}

// ---------- multisplit, 2-pass: hist+reserve, then re-read & place ----------
__global__ __launch_bounds__(1024) void k_msplit3(const int* __restrict__ eidx,
                                                  int* __restrict__ binCursor,
                                                  unsigned int* __restrict__ binned,
                                                  int* __restrict__ ovfCnt,
                                                  v2i* __restrict__ ovf,
                                                  int E, int NB, int cap) {
    __shared__ int hist[256], base[256];
    __shared__ int stF;
    int t = threadIdx.x;
    if (t == 0) {           // int32 vs int64 detect (odd words of first 64 i64 all 0)
        int o = 0;
        for (int j = 1; j < 128; j += 2) o |= eidx[j];
        stF = (o == 0) ? 2 : 1;
    }
    __syncthreads();
    int st = stF;
    int ntiles = (E + MS_TILE - 1) / MS_TILE;

    for (int tile = blockIdx.x; tile < ntiles; tile += gridDim.x) {
        int e0 = tile * MS_TILE;
        int e1 = min(e0 + MS_TILE, E);

        if (t < 256) hist[t] = 0;
        __syncthreads();
        for (int e = e0 + t; e < e1; e += 1024) {
            int d = (st == 2) ? ((const v2i*)eidx)[E + e].x : eidx[E + e];
            atomicAdd(&hist[d >> BSH], 1);
        }
        __syncthreads();
        if (t < NB && hist[t] > 0) base[t] = atomicAdd(&binCursor[t], hist[t]);
        __syncthreads();
        if (t < 256) hist[t] = 0;   // reuse as rank counters
        __syncthreads();
        for (int e = e0 + t; e < e1; e += 1024) {
            int s, d;
            if (st == 2) {
                s = ((const v2i*)eidx)[e].x;
                d = ((const v2i*)eidx)[E + e].x;
            } else {
                s = eidx[e];
                d = eidx[E + e];
            }
            int b = d >> BSH;
            int r = atomicAdd(&hist[b], 1);
            int local = base[b] + r;
            if (local < cap) {
                binned[(size_t)b * cap + local] =
                    ((unsigned int)s << BSH) | (unsigned int)(d & (BINSZ - 1));
            } else {
                int o = atomicAdd(ovfCnt, 1);
                if (o < OVF_CAP) ovf[o] = (v2i){s, d};
            }
        }
        __syncthreads();
    }
}

// ---------- fused fill: bin prefix (in-block) + hist + scan -> offsets/dinv/
// cursor; stage + flush csr.
__global__ __launch_bounds__(512) void k_fillA(const unsigned int* __restrict__ binned,
                                               const int* __restrict__ binCursor,
                                               int* __restrict__ offsets,
                                               int* __restrict__ cursor,
                                               float* __restrict__ dinv,
                                               int* __restrict__ csr,
                                               int cap, int NB, int N) {
    __shared__ int hist[BINSZ], scanS[BINSZ], curL[BINSZ];
    __shared__ unsigned int stage[CAPL];
    __shared__ int gbaseS;
    int b = blockIdx.x;
    int t = threadIdx.x;
    int g0 = b << BSH;
    int g = g0 + t;
    int n = min(binCursor[b], cap);
    const unsigned int* p = binned + (size_t)b * cap;

    if (t < 64) {           // wave 0: exclusive prefix of bins [0,b)
        int acc = 0;
        for (int i = t; i < b; i += 64) acc += min(binCursor[i], cap);
#pragma unroll
        for (int off = 32; off > 0; off >>= 1) acc += __shfl_xor(acc, off, 64);
        if (t == 0) gbaseS = acc;
    }
    hist[t] = 0;
    __syncthreads();
    for (int i = t; i < n; i += 512)
        atomicAdd(&hist[p[i] & (BINSZ - 1)], 1);
    __syncthreads();
    int h = hist[t];
    scanS[t] = h;
    __syncthreads();
    for (int d = 1; d < 512; d <<= 1) {
        int add = (t >= d) ? scanS[t - d] : 0;
        __syncthreads();
        scanS[t] += add;
        __syncthreads();
    }
    int excl = scanS[t] - h;
    int gbase = gbaseS;
    if (g < N) {
        offsets[g] = gbase + excl;
        dinv[g] = rsqrtf((float)(h + 1));
    }
    if (t == 511) offsets[min(g0 + BINSZ, N)] = gbase + scanS[511];  // race-benign dup

    curL[t] = excl;
    __syncthreads();
    int nl = min(n, CAPL);
    for (int i = t; i < nl; i += 512) {
        unsigned int w = p[i];
        int pos = atomicAdd(&curL[w & (BINSZ - 1)], 1);
        if (pos < CAPL) stage[pos] = w >> BSH;
    }
    __syncthreads();
    if (g < N) cursor[g] = gbase + curL[t];     // final positions (ovf valve)
    for (int i = t; i < nl; i += 512)
        csr[gbase + i] = (int)stage[i];         // coalesced flush
    __syncthreads();
    for (int i = CAPL + t; i < n; i += 512) {   // dead by construction
        unsigned int w = p[i];
        int pos = atomicAdd(&cursor[g0 + (int)(w & (BINSZ - 1))], 1);
        csr[pos] = (int)(w >> BSH);
    }
}

// ---------- GEMM1: h1' = (x @ W1) * dinv[row], fp16-packed [N,32] __half2 ----------
// Trailing block drains the (always-empty) overflow valve.
__global__ __launch_bounds__(256) void k_gemm1t(const float* __restrict__ x,
                                                const float* __restrict__ W,
                                                const float* __restrict__ dinv,
                                                __half2* __restrict__ h1, int N,
                                                const int* __restrict__ ovfCnt,
                                                const v2i* __restrict__ ovf,
                                                int* __restrict__ cursor,
                                                int* __restrict__ csr) {
    int t = threadIdx.x;
    if (blockIdx.x == gridDim.x - 1) {          // overflow drain block
        int n = min(*ovfCnt, OVF_CAP);
        for (int i = t; i < n; i += 256) {
            v2i e = ovf[i];
            int pos = atomicAdd(&cursor[e.y], 1);
            csr[pos] = e.x;
        }
        return;
    }

    __shared__ __half xsT[DIM_IN * 64];     // [k][row] transposed tile, 16KB fp16
    __shared__ float Ws[DIM_IN * DIM_HID];  // [k][col], 32KB
    int row0 = blockIdx.x * 64;

#pragma unroll
    for (int i = 0; i < 8; i++)
        ((float4*)Ws)[t + 256 * i] = ((const float4*)W)[t + 256 * i];

#pragma unroll
    for (int i = 0; i < 8; i++) {
        int idx = t * 8 + i;
        int r = idx >> 5;
        int kc = idx & 31;
        int row = row0 + r;
        float4 v = (row < N) ? ((const float4*)(x + (size_t)row * DIM_IN))[kc]
                             : make_float4(0.f, 0.f, 0.f, 0.f);
        xsT[(4 * kc + 0) * 64 + r] = __float2half(v.x);
        xsT[(4 * kc + 1) * 64 + r] = __float2half(v.y);
        xsT[(4 * kc + 2) * 64 + r] = __float2half(v.z);
        xsT[(4 * kc + 3) * 64 + r] = __float2half(v.w);
    }
    __syncthreads();

    int c = t & 15;
    int r = t >> 4;
    float acc[4][4] = {};

#pragma unroll 4
    for (int k = 0; k < DIM_IN; k++) {
        __half2 xh01 = *(const __half2*)&xsT[k * 64 + 4 * r];
        __half2 xh23 = *(const __half2*)&xsT[k * 64 + 4 * r + 2];
        float2 x01 = __half22float2(xh01);
        float2 x23 = __half22float2(xh23);
        float4 wb = *(const float4*)&Ws[k * DIM_HID + 4 * c];
        float xi[4] = {x01.x, x01.y, x23.x, x23.y};
#pragma unroll
        for (int i = 0; i < 4; i++) {
            acc[i][0] = fmaf(xi[i], wb.x, acc[i][0]);
            acc[i][1] = fmaf(xi[i], wb.y, acc[i][1]);
            acc[i][2] = fmaf(xi[i], wb.z, acc[i][2]);
            acc[i][3] = fmaf(xi[i], wb.w, acc[i][3]);
        }
    }

#pragma unroll
    for (int i = 0; i < 4; i++) {
        int row = row0 + 4 * r + i;
        if (row < N) {
            float d = dinv[row];
            h1[(size_t)row * 32 + 2 * c] = __floats2half2_rn(acc[i][0] * d, acc[i][1] * d);
            h1[(size_t)row * 32 + 2 * c + 1] = __floats2half2_rn(acc[i][2] * d, acc[i][3] * d);
        }
    }
}

// ---------- agg1: g = relu(di*(sum h1'[src] + h1'[node]) + b1); h2' = (g@W2)*di ----------
// R21: 4-deep load batching on the full-chunk fast path (4 uint4 gathers in
// flight per lane; R19 2-deep gave +9%, R20 residency gave +9% -- same lever).
__global__ __launch_bounds__(256, 8) void k_agg1(const __half2* __restrict__ h1,
                                                 const int* __restrict__ csr,
                                                 const int* __restrict__ offsets,
                                                 const float* __restrict__ dinv,
                                                 const float* __restrict__ b1,
                                                 const float* __restrict__ W2,
                                                 float4* __restrict__ h2, int N) {
    __shared__ float W2s[DIM_HID * 3];
    __shared__ float b1s[DIM_HID];
    int t = threadIdx.x;
    if (t < DIM_HID * 3) W2s[t] = W2[t];
    if (t < DIM_HID) b1s[t] = b1[t];
    __syncthreads();

    int hl = t & 31;
    int slot = hl >> 3;      // 0..3 edge slot
    int f8 = hl & 7;         // feature octet (features 8*f8 .. 8*f8+7)
    int node = blockIdx.x * 8 + (t >> 5);
    if (node >= N) return;

    const uint4* h1q = (const uint4*)h1;   // row = 8 x uint4 (128B)
    float di = dinv[node];
    int beg = offsets[node], end = offsets[node + 1];

    __half2 a0, a1, a2, a3;
    if (slot == 0) {                       // self-loop (pre-scaled)
        uint4 v = h1q[(size_t)node * 8 + f8];
        a0 = u2h(v.x); a1 = u2h(v.y); a2 = u2h(v.z); a3 = u2h(v.w);
    } else {
        a0 = a1 = a2 = a3 = __floats2half2_rn(0.f, 0.f);
    }

    for (int base = beg; base < end; base += 32) {
        int cnt = min(32, end - base);
        int sidx = (hl < cnt) ? csr[base + hl] : 0;
        if (cnt == 32) {                   // fast path: 4-deep batched gathers
            int s0 = __shfl(sidx, slot, 32);
            int s1 = __shfl(sidx, slot + 4, 32);
            int s2 = __shfl(sidx, slot + 8, 32);
            int s3 = __shfl(sidx, slot + 12, 32);
            uint4 v0 = h1q[(size_t)s0 * 8 + f8];
            uint4 v1 = h1q[(size_t)s1 * 8 + f8];
            uint4 v2 = h1q[(size_t)s2 * 8 + f8];
            uint4 v3 = h1q[(size_t)s3 * 8 + f8];
            a0 = __hadd2(a0, u2h(v0.x)); a1 = __hadd2(a1, u2h(v0.y));
            a2 = __hadd2(a2, u2h(v0.z)); a3 = __hadd2(a3, u2h(v0.w));
            a0 = __hadd2(a0, u2h(v1.x)); a1 = __hadd2(a1, u2h(v1.y));
            a2 = __hadd2(a2, u2h(v1.z)); a3 = __hadd2(a3, u2h(v1.w));
            a0 = __hadd2(a0, u2h(v2.x)); a1 = __hadd2(a1, u2h(v2.y));
            a2 = __hadd2(a2, u2h(v2.z)); a3 = __hadd2(a3, u2h(v2.w));
            a0 = __hadd2(a0, u2h(v3.x)); a1 = __hadd2(a1, u2h(v3.y));
            a2 = __hadd2(a2, u2h(v3.z)); a3 = __hadd2(a3, u2h(v3.w));
            s0 = __shfl(sidx, slot + 16, 32);
            s1 = __shfl(sidx, slot + 20, 32);
            s2 = __shfl(sidx, slot + 24, 32);
            s3 = __shfl(sidx, slot + 28, 32);
            v0 = h1q[(size_t)s0 * 8 + f8];
            v1 = h1q[(size_t)s1 * 8 + f8];
            v2 = h1q[(size_t)s2 * 8 + f8];
            v3 = h1q[(size_t)s3 * 8 + f8];
            a0 = __hadd2(a0, u2h(v0.x)); a1 = __hadd2(a1, u2h(v0.y));
            a2 = __hadd2(a2, u2h(v0.z)); a3 = __hadd2(a3, u2h(v0.w));
            a0 = __hadd2(a0, u2h(v1.x)); a1 = __hadd2(a1, u2h(v1.y));
            a2 = __hadd2(a2, u2h(v1.z)); a3 = __hadd2(a3, u2h(v1.w));
            a0 = __hadd2(a0, u2h(v2.x)); a1 = __hadd2(a1, u2h(v2.y));
            a2 = __hadd2(a2, u2h(v2.z)); a3 = __hadd2(a3, u2h(v2.w));
            a0 = __hadd2(a0, u2h(v3.x)); a1 = __hadd2(a1, u2h(v3.y));
            a2 = __hadd2(a2, u2h(v3.z)); a3 = __hadd2(a3, u2h(v3.w));
        } else {                           // tail
            int iters = (cnt + 3) >> 2;
            for (int j = 0; j < iters; j++) {
                int idx = 4 * j + slot;
                int s = __shfl(sidx, idx, 32);
                if (idx < cnt) {
                    uint4 v = h1q[(size_t)s * 8 + f8];
                    a0 = __hadd2(a0, u2h(v.x)); a1 = __hadd2(a1, u2h(v.y));
                    a2 = __hadd2(a2, u2h(v.z)); a3 = __hadd2(a3, u2h(v.w));
                }
            }
        }
    }

    // reduce across the 4 edge-slots (lanes hl^8, hl^16 within the half-wave)
    a0 = __hadd2(a0, h2_shfl_xor(a0, 8));  a0 = __hadd2(a0, h2_shfl_xor(a0, 16));
    a1 = __hadd2(a1, h2_shfl_xor(a1, 8));  a1 = __hadd2(a1, h2_shfl_xor(a1, 16));
    a2 = __hadd2(a2, h2_shfl_xor(a2, 8));  a2 = __hadd2(a2, h2_shfl_xor(a2, 16));
    a3 = __hadd2(a3, h2_shfl_xor(a3, 8));  a3 = __hadd2(a3, h2_shfl_xor(a3, 16));

    if (slot == 0) {                       // epilogue on 8 lanes per node
        float2 f0 = __half22float2(a0), f1 = __half22float2(a1);
        float2 f2 = __half22float2(a2), f3 = __half22float2(a3);
        float acc[8] = {f0.x, f0.y, f1.x, f1.y, f2.x, f2.y, f3.x, f3.y};
        float v0 = 0.f, v1 = 0.f, v2 = 0.f;
#pragma unroll
        for (int k = 0; k < 8; k++) {
            int f = 8 * f8 + k;
            float gg = fmaxf(fmaf(acc[k], di, b1s[f]), 0.f);
            v0 = fmaf(gg, W2s[f * 3 + 0], v0);
            v1 = fmaf(gg, W2s[f * 3 + 1], v1);
            v2 = fmaf(gg, W2s[f * 3 + 2], v2);
        }
#pragma unroll
        for (int off = 4; off > 0; off >>= 1) {
            v0 += __shfl_xor(v0, off, 8);
            v1 += __shfl_xor(v1, off, 8);
            v2 += __shfl_xor(v2, off, 8);
        }
        if (f8 == 0) h2[node] = make_float4(v0 * di, v1 * di, v2 * di, 0.f);
    }
}

// ---------- agg2: out = di*(sum h2'[src] + h2'[node]) + b2 ----------
__global__ __launch_bounds__(256) void k_agg2(const float4* __restrict__ h2,
                                              const int* __restrict__ csr,
                                              const int* __restrict__ offsets,
                                              const float* __restrict__ dinv,
                                              const float* __restrict__ b2,
                                              float* __restrict__ out, int N) {
    int t = threadIdx.x;
    int l = t & 7;
    int node = blockIdx.x * 32 + (t >> 3);
    if (node >= N) return;

    float di = dinv[node];
    int beg = offsets[node], end = offsets[node + 1];
    float a0 = 0.f, a1 = 0.f, a2 = 0.f;
    for (int e = beg + l; e < end; e += 8) {
        float4 h = h2[csr[e]];
        a0 += h.x;
        a1 += h.y;
        a2 += h.z;
    }
#pragma unroll
    for (int off = 4; off > 0; off >>= 1) {
        a0 += __shfl_xor(a0, off, 8);
        a1 += __shfl_xor(a1, off, 8);
        a2 += __shfl_xor(a2, off, 8);
    }
    if (l == 0) {
        float4 hs = h2[node];
        out[(size_t)node * 3 + 0] = fmaf(a0 + hs.x, di, b2[0]);
        out[(size_t)node * 3 + 1] = fmaf(a1 + hs.y, di, b2[1]);
        out[(size_t)node * 3 + 2] = fmaf(a2 + hs.z, di, b2[2]);
    }
}

extern "C" void kernel_launch(void* const* d_in, const int* in_sizes, int n_in,
                              void* d_out, int out_size, void* d_ws, size_t ws_size,
                              hipStream_t stream) {
    const float* x = (const float*)d_in[0];
    const int* eidx = (const int*)d_in[1];
    const float* W1 = (const float*)d_in[2];
    const float* b1 = (const float*)d_in[3];
    const float* W2 = (const float*)d_in[4];
    const float* b2 = (const float*)d_in[5];
    float* out = (float*)d_out;

    const int N = in_sizes[0] / DIM_IN;     // 100000
    const int E = in_sizes[1] / 2;          // 3200000
    const int NB = (N + BINSZ - 1) >> BSH;  // 196 bins of 512 nodes

    char* w = (char*)d_ws;
    size_t off = 0;
    auto carve = [&](size_t bytes) -> char* {
        char* p = w + off;
        off += (bytes + 255) & ~(size_t)255;
        return p;
    };
    int* offsets = (int*)carve((size_t)(N + 1) * 4);
    int* cursor = (int*)carve((size_t)N * 4);
    float* dinv = (float*)carve((size_t)N * 4);
    int* csr = (int*)carve((size_t)E * 4);
    int* binCursor = (int*)carve(MAXNB * 4);
    int* ovfCnt = (int*)carve(16);
    v2i* ovf = (v2i*)carve((size_t)OVF_CAP * 8);
    float4* h2 = (float4*)carve((size_t)N * 16);

    // uni region: packed binned words (msplit..fillA), then aliased by fp16 h1'.
    size_t h1_bytes = (size_t)N * DIM_HID * 2;
    int capDes = E / NB + E / NB / 16 + 256;     // mean + margin; < CAPL by construction
    size_t binned_des = (size_t)NB * capDes * 4;
    size_t uni_avail = (ws_size > off + 256) ? (ws_size - off - 256) : h1_bytes;
    size_t uni_bytes = binned_des > h1_bytes ? binned_des : h1_bytes;
    if (uni_bytes > uni_avail) uni_bytes = uni_avail > h1_bytes ? uni_avail : h1_bytes;
    char* uni = carve(uni_bytes);
    unsigned int* binned = (unsigned int*)uni;
    __half2* h1 = (__half2*)uni;        // aliased: valid only after k_fillA
    int cap = (int)(uni_bytes / ((size_t)NB * 4));
    if (cap > capDes) cap = capDes;
    if (cap > CAPL) cap = CAPL;         // keep the fillA stage invariant

    (void)hipMemsetAsync(binCursor, 0, MAXNB * 4 + 256, stream);  // binCursor + ovfCnt

    int ntiles = (E + MS_TILE - 1) / MS_TILE;
    k_msplit3<<<ntiles, 1024, 0, stream>>>(eidx, binCursor, binned, ovfCnt, ovf,
                                           E, NB, cap);
    k_fillA<<<NB, 512, 0, stream>>>(binned, binCursor, offsets, cursor,
                                    dinv, csr, cap, NB, N);
    k_gemm1t<<<(N + 63) / 64 + 1, 256, 0, stream>>>(x, W1, dinv, h1, N,
                                                    ovfCnt, ovf, cursor, csr);
    k_agg1<<<(N + 7) / 8, 256, 0, stream>>>(h1, csr, offsets, dinv, b1, W2, h2, N);
    k_agg2<<<(N + 31) / 32, 256, 0, stream>>>(h2, csr, offsets, dinv, b2, out, N);
}